// Round 6
// baseline (64.593 us; speedup 1.0000x reference)
//
#include <hip/hip_runtime.h>
#include <cstdint>
#include <cstddef>

// ===========================================================================
// Compile-time replication of numpy default_rng(0) forest generation
// (SeedSequence(0) -> PCG64 -> Generator.integers(0,i), Lemire int64 path).
// Validated on-HW rounds 2-4 (absmax ~1e6-4e6 vs 1.04e12 threshold).
// ===========================================================================
namespace cx {

constexpr uint32_t hashmix(uint32_t value, uint32_t& hc) {
    value ^= hc; hc *= 0x931e8875u; value *= hc; value ^= value >> 16; return value;
}
constexpr uint32_t mixf(uint32_t x, uint32_t y) {
    uint32_t r = x * 0xca01f9ddu - y * 0x4973f715u; r ^= r >> 16; return r;
}

struct Pcg64 {
    unsigned __int128 state{}, inc{};
    bool has_uint32{}; uint32_t uinteger{};
    static constexpr unsigned __int128 mult() {
        return (((unsigned __int128)2549297995355413924ULL) << 64) | 4865540595714422341ULL;
    }
    constexpr void step() { state = state * mult() + inc; }
    constexpr void seed_default0() {
        uint32_t pool[4] = {0, 0, 0, 0};
        uint32_t hc = 0x43b0d7e5u;  // INIT_A
        for (int i = 0; i < 4; ++i) pool[i] = hashmix(0u, hc);
        for (int isrc = 0; isrc < 4; ++isrc)
            for (int idst = 0; idst < 4; ++idst)
                if (isrc != idst) pool[idst] = mixf(pool[idst], hashmix(pool[isrc], hc));
        uint32_t st[8] = {};
        uint32_t hc2 = 0x8b51f9ddu;  // INIT_B
        for (int i = 0; i < 8; ++i) {
            uint32_t dv = pool[i & 3];
            dv ^= hc2; hc2 *= 0x58f38dedu; dv *= hc2; dv ^= dv >> 16;
            st[i] = dv;
        }
        const uint64_t v0 = (uint64_t)st[0] | ((uint64_t)st[1] << 32);
        const uint64_t v1 = (uint64_t)st[2] | ((uint64_t)st[3] << 32);
        const uint64_t v2 = (uint64_t)st[4] | ((uint64_t)st[5] << 32);
        const uint64_t v3 = (uint64_t)st[6] | ((uint64_t)st[7] << 32);
        const unsigned __int128 s = (((unsigned __int128)v0) << 64) | v1;
        const unsigned __int128 i_ = (((unsigned __int128)v2) << 64) | v3;
        state = 0; inc = (i_ << 1) | 1;
        step(); state += s; step();
        has_uint32 = false; uinteger = 0;
    }
    constexpr uint64_t next64() {
        step();
        const uint64_t hi = (uint64_t)(state >> 64), lo = (uint64_t)state;
        const uint64_t x = hi ^ lo;
        const unsigned rot = (unsigned)(state >> 122);
        return (x >> rot) | (x << ((64u - rot) & 63u));
    }
    constexpr uint32_t next32() {
        if (has_uint32) { has_uint32 = false; return uinteger; }
        const uint64_t n = next64();
        has_uint32 = true; uinteger = (uint32_t)(n >> 32);
        return (uint32_t)n;
    }
    constexpr uint32_t bounded_lemire32(uint32_t rng) {
        const uint32_t rng_excl = rng + 1u;
        uint64_t m = (uint64_t)next32() * (uint64_t)rng_excl;
        uint32_t leftover = (uint32_t)m;
        if (leftover < rng_excl) {
            const uint32_t threshold = (0xFFFFFFFFu - rng) % rng_excl;
            while (leftover < threshold) {
                m = (uint64_t)next32() * (uint64_t)rng_excl;
                leftover = (uint32_t)m;
            }
        }
        return (uint32_t)(m >> 32);
    }
    constexpr int64_t integers0(int64_t high) {
        const uint64_t rng = (uint64_t)(high - 1);
        if (rng == 0) return 0;  // no RNG consumption
        return (int64_t)bounded_lemire32((uint32_t)rng);
    }
};

// ===========================================================================
// Compile-time plan: distinct proper-subtree series (one scan each, computed
// once for the WHOLE forest), root formulas, levels, liveness slot allocation.
// w_s = x * prod_children C_child ; C_s = exclusive cumsum w_s.
// Root: T~_r = sum_t x * prod C_child. Series 0 = leaf (C0 = exclusive cumsum x).
// ===========================================================================
constexpr int NTREE = 32, MAXSER = 32, MAXROOT = 32, MAXFAC = 5, MAXSLOT = 12;

struct Plan {
    int nser, nroot, nslot, maxlvl;
    int lvl[MAXSER];
    int slot[MAXSER];
    int nfac[MAXSER];
    int fac[MAXSER][4];
    int rnfac[MAXROOT];
    int rfac[MAXROOT][MAXFAC];
    int rlvl[MAXROOT];
    int tree_root[NTREE];
};

constexpr Plan build_plan() {
    Plan P{};
    unsigned skey[MAXSER] = {}, rkey[MAXROOT] = {};
    P.nser = 1; skey[0] = (2u << 16) | 2u;  // leaf canonical code "10"
    P.nfac[0] = 0;
    P.nroot = 0;

    Pcg64 rng; rng.seed_default0();
    for (int t = 0; t < NTREE; ++t) {
        int par[6] = {0, 0, 0, 0, 0, 0};
        for (int i = 1; i <= 5; ++i) par[i] = (int)rng.integers0(i);
        int ch[6][5] = {}; int nch[6] = {};
        for (int i = 1; i <= 5; ++i) ch[par[i]][nch[par[i]]++] = i;

        int sid[6] = {}; unsigned keyn[6] = {};
        for (int i = 5; i >= 1; --i) {
            const int n = nch[i];
            unsigned ck[5] = {}; int cf[5] = {};
            for (int k = 0; k < n; ++k) { ck[k] = keyn[ch[i][k]]; cf[k] = sid[ch[i][k]]; }
            for (int a = 0; a < n; ++a)   // sort keys desc (canonical), ids asc (product order)
                for (int bq = a + 1; bq < n; ++bq) {
                    if (ck[bq] > ck[a]) { unsigned tmp = ck[a]; ck[a] = ck[bq]; ck[bq] = tmp; }
                    if (cf[bq] < cf[a]) { int tmp = cf[a]; cf[a] = cf[bq]; cf[bq] = tmp; }
                }
            unsigned bits = 1u, len = 1u;
            for (int k = 0; k < n; ++k) { bits = (bits << (ck[k] >> 16)) | (ck[k] & 0xffffu); len += ck[k] >> 16; }
            bits <<= 1; len += 1;
            const unsigned key = (len << 16) | bits;
            keyn[i] = key;
            int id = -1;
            for (int q = 0; q < P.nser; ++q) if (skey[q] == key) { id = q; break; }
            if (id < 0) {
                id = P.nser++;
                skey[id] = key; P.nfac[id] = n;
                for (int k = 0; k < n; ++k) P.fac[id][k] = cf[k];
            }
            sid[i] = id;
        }
        {   // root shape
            const int n = nch[0];
            unsigned ck[5] = {}; int cf[5] = {};
            for (int k = 0; k < n; ++k) { ck[k] = keyn[ch[0][k]]; cf[k] = sid[ch[0][k]]; }
            for (int a = 0; a < n; ++a)
                for (int bq = a + 1; bq < n; ++bq) {
                    if (ck[bq] > ck[a]) { unsigned tmp = ck[a]; ck[a] = ck[bq]; ck[bq] = tmp; }
                    if (cf[bq] < cf[a]) { int tmp = cf[a]; cf[a] = cf[bq]; cf[bq] = tmp; }
                }
            unsigned bits = 1u, len = 1u;
            for (int k = 0; k < n; ++k) { bits = (bits << (ck[k] >> 16)) | (ck[k] & 0xffffu); len += ck[k] >> 16; }
            bits <<= 1; len += 1;
            const unsigned key = (len << 16) | bits;
            int id = -1;
            for (int q = 0; q < P.nroot; ++q) if (rkey[q] == key) { id = q; break; }
            if (id < 0) {
                id = P.nroot++;
                rkey[id] = key; P.rnfac[id] = n;
                for (int k = 0; k < n; ++k) P.rfac[id][k] = cf[k];
            }
            P.tree_root[t] = id;
        }
    }
    // levels (factors always have smaller id -> single pass)
    P.lvl[0] = 0; P.maxlvl = 0;
    for (int s = 1; s < P.nser; ++s) {
        int m = 0;
        for (int k = 0; k < P.nfac[s]; ++k) { const int l = P.lvl[P.fac[s][k]]; if (l > m) m = l; }
        P.lvl[s] = m + 1;
        if (m + 1 > P.maxlvl) P.maxlvl = m + 1;
    }
    for (int r = 0; r < P.nroot; ++r) {
        int m = 0;
        for (int k = 0; k < P.rnfac[r]; ++k) { const int l = P.lvl[P.rfac[r][k]]; if (l > m) m = l; }
        P.rlvl[r] = m;
    }
    // last-use level per series
    int last[MAXSER] = {};
    for (int s = 0; s < P.nser; ++s) last[s] = 0;
    for (int s = 1; s < P.nser; ++s)
        for (int k = 0; k < P.nfac[s]; ++k) { const int f = P.fac[s][k]; if (P.lvl[s] > last[f]) last[f] = P.lvl[s]; }
    for (int r = 0; r < P.nroot; ++r)
        for (int k = 0; k < P.rnfac[r]; ++k) { const int f = P.rfac[r][k]; if (P.rlvl[r] > last[f]) last[f] = P.rlvl[r]; }
    // greedy slot allocation (free at last_use+1; dst of level L never aliases a
    // factor still consumed at level >= L because those have free_at >= L+1)
    int free_at[MAXSLOT] = {};
    for (int q = 0; q < MAXSLOT; ++q) free_at[q] = -1000;
    P.nslot = 0;
    for (int L = 0; L <= P.maxlvl; ++L)
        for (int s = 0; s < P.nser; ++s) {
            if (P.lvl[s] != L) continue;
            int pick = -1;
            for (int q = 0; q < MAXSLOT; ++q) if (free_at[q] <= L) { pick = q; break; }
            P.slot[s] = pick;
            free_at[pick] = last[s] + 1;
            if (pick + 1 > P.nslot) P.nslot = pick + 1;
        }
    return P;
}

constexpr Plan PL = build_plan();
static_assert(PL.nser <= MAXSER && PL.nroot <= MAXROOT, "plan overflow");
static_assert(PL.nslot <= MAXSLOT && PL.maxlvl <= 9, "plan overflow");
static_assert(PL.nslot >= 1 && PL.nser >= 1 && PL.nroot >= 1, "plan degenerate");

}  // namespace cx

// ===========================================================================
// Device: DPP wave scan (gfx9 canonical: row_shr 1/2/4/8 + row_bcast 15/31).
// Validated on-HW rounds 3-4.
// ===========================================================================
template <int CTRL, int RM>
__device__ __forceinline__ float dppmov(float x) {
    return __builtin_bit_cast(float,
        __builtin_amdgcn_update_dpp(0, __builtin_bit_cast(int, x), CTRL, RM, 0xf, false));
}
__device__ __forceinline__ float wave_incl_scan(float v) {
    v += dppmov<0x111, 0xf>(v);
    v += dppmov<0x112, 0xf>(v);
    v += dppmov<0x114, 0xf>(v);
    v += dppmov<0x118, 0xf>(v);
    v += dppmov<0x142, 0xa>(v);  // row_bcast:15 -> rows 1,3
    v += dppmov<0x143, 0xc>(v);  // row_bcast:31 -> rows 2,3
    return v;                    // inclusive; lane63 = wave total
}

struct OutMap { unsigned char m[32]; };

// ===========================================================================
// 512 threads x 8 elems/thread (T=4096). Fully unrolled from constexpr plan.
// Per level L: [pre: exclusive-local cumsum -> dst slot (FMA chain fusing the
// last factor), DPP wave scan, wave-total -> LDS] barrier [post: base += carry,
// S[ds][:] += base] [root reduces at rlvl L via FMA chains]; final barrier.
// ===========================================================================
#define THREADS 512
#define ELEM 8
#define NWAVE 8

__global__ __launch_bounds__(THREADS, 6) void fis_kernel(const float* __restrict__ x,
                                                         const float* __restrict__ alphas,
                                                         float* __restrict__ out,
                                                         const OutMap om) {
    using cx::PL;
    constexpr int NSER = PL.nser, NROOT = PL.nroot, NSLOT = PL.nslot, MAXL = PL.maxlvl;

    const int tid = threadIdx.x;
    const int lane = tid & 63;
    const int wv = tid >> 6;
    const int b = blockIdx.x >> 7;   // CH = 128
    const int c = blockIdx.x & 127;

    __shared__ float s_w[NSER + NROOT][NWAVE];

    float xr[ELEM];
    {
        const float4* xv = reinterpret_cast<const float4*>(
            x + (((size_t)b << 7) + (size_t)c) * 4096 + (size_t)tid * ELEM);
        const float4 v0 = xv[0], v1 = xv[1];
        xr[0] = v0.x; xr[1] = v0.y; xr[2] = v0.z; xr[3] = v0.w;
        xr[4] = v1.x; xr[5] = v1.y; xr[6] = v1.z; xr[7] = v1.w;
    }

    float S[NSLOT][ELEM];   // compile-time indexed after unroll -> registers
    float wex[cx::MAXSER];  // per-scan carried scalar (exclusive-in-wave offset)

#pragma unroll
    for (int L = 0; L <= MAXL; ++L) {
        // ---- pre-phase: scans at level L ----
#pragma unroll
        for (int s = 0; s < NSER; ++s) {
            if (PL.lvl[s] != L) continue;
            const int ds = PL.slot[s];
            float run = 0.f;
            if (PL.nfac[s] == 0) {
                // leaf series: exclusive local cumsum of x
#pragma unroll
                for (int j = 0; j < ELEM; ++j) { S[ds][j] = run; run += xr[j]; }
            } else {
                float v[ELEM];
#pragma unroll
                for (int j = 0; j < ELEM; ++j) v[j] = xr[j];
#pragma unroll
                for (int k = 0; k < 3; ++k) {          // all factors but the last
                    if (k < PL.nfac[s] - 1) {
                        const int fs = PL.slot[PL.fac[s][k]];
#pragma unroll
                        for (int j = 0; j < ELEM; ++j) v[j] *= S[fs][j];
                    }
                }
                const int fl = PL.slot[PL.fac[s][PL.nfac[s] - 1]];
#pragma unroll
                for (int j = 0; j < ELEM; ++j) {       // fused: run += v*C_last
                    S[ds][j] = run;
                    run = __builtin_fmaf(v[j], S[fl][j], run);
                }
            }
            const float wi = wave_incl_scan(run);
            if (lane == 63) s_w[s][wv] = wi;           // wave total
            wex[s] = wi - run;                         // exclusive within wave
        }
        __syncthreads();
        // ---- post-phase: finish exclusive cumsum ----
#pragma unroll
        for (int s = 0; s < NSER; ++s) {
            if (PL.lvl[s] != L) continue;
            const int ds = PL.slot[s];
            float base = wex[s];
#pragma unroll
            for (int k = 0; k < NWAVE - 1; ++k)
                if (k < wv) base += s_w[s][k];
#pragma unroll
            for (int j = 0; j < ELEM; ++j) S[ds][j] += base;
        }
        // ---- root reduces whose deepest factor is level L ----
#pragma unroll
        for (int r = 0; r < NROOT; ++r) {
            if (PL.rlvl[r] != L) continue;
            float v[ELEM];
#pragma unroll
            for (int j = 0; j < ELEM; ++j) v[j] = xr[j];
#pragma unroll
            for (int k = 0; k < 4; ++k) {              // all factors but the last
                if (k < PL.rnfac[r] - 1) {
                    const int fs = PL.slot[PL.rfac[r][k]];
#pragma unroll
                    for (int j = 0; j < ELEM; ++j) v[j] *= S[fs][j];
                }
            }
            const int fl = PL.slot[PL.rfac[r][PL.rnfac[r] - 1]];
            float acc = 0.f;
#pragma unroll
            for (int j = 0; j < ELEM; ++j) acc = __builtin_fmaf(v[j], S[fl][j], acc);
            const float wr = wave_incl_scan(acc);
            if (lane == 63) s_w[NSER + r][wv] = wr;    // per-wave partial
        }
    }

    __syncthreads();
    if (tid < 32) {
        const int rid = om.m[tid];
        float T = 0.f;
#pragma unroll
        for (int k = 0; k < NWAVE; ++k) T += s_w[NSER + rid][k];
        const float* ap = alphas + tid * 768 + c;  // alphas[tree, i, c] : [32,6,128]
        const float aprod = ap[0] * ap[128] * ap[256] * ap[384] * ap[512] * ap[640];
        out[(((size_t)b << 5) + (size_t)tid) * 128 + c] = aprod * T;
    }
}

// ===========================================================================
extern "C" void kernel_launch(void* const* d_in, const int* in_sizes, int n_in,
                              void* d_out, int out_size, void* d_ws, size_t ws_size,
                              hipStream_t stream) {
    const float* x = (const float*)d_in[0];       // [16,128,4096] f32
    const float* alphas = (const float*)d_in[1];  // [32,6,128]    f32
    float* out = (float*)d_out;                   // [16,32,128]   f32

    OutMap om;
    for (int t = 0; t < cx::NTREE; ++t) om.m[t] = (unsigned char)cx::PL.tree_root[t];

    fis_kernel<<<dim3(16 * 128), dim3(THREADS), 0, stream>>>(x, alphas, out, om);
}

// Round 7
// 24.787 us; speedup vs baseline: 2.6060x; 2.6060x over previous
//
#include <hip/hip_runtime.h>
#include <cstdint>
#include <cstddef>

// ===========================================================================
// Compile-time replication of numpy default_rng(0) forest generation
// (SeedSequence(0) -> PCG64 -> Generator.integers(0,i), Lemire int64 path).
// Validated on-HW rounds 2-6 (absmax ~1e6-1.7e7 vs 1.04e12 threshold).
// ===========================================================================
namespace cx {

constexpr uint32_t hashmix(uint32_t value, uint32_t& hc) {
    value ^= hc; hc *= 0x931e8875u; value *= hc; value ^= value >> 16; return value;
}
constexpr uint32_t mixf(uint32_t x, uint32_t y) {
    uint32_t r = x * 0xca01f9ddu - y * 0x4973f715u; r ^= r >> 16; return r;
}

struct Pcg64 {
    unsigned __int128 state{}, inc{};
    bool has_uint32{}; uint32_t uinteger{};
    static constexpr unsigned __int128 mult() {
        return (((unsigned __int128)2549297995355413924ULL) << 64) | 4865540595714422341ULL;
    }
    constexpr void step() { state = state * mult() + inc; }
    constexpr void seed_default0() {
        uint32_t pool[4] = {0, 0, 0, 0};
        uint32_t hc = 0x43b0d7e5u;  // INIT_A
        for (int i = 0; i < 4; ++i) pool[i] = hashmix(0u, hc);
        for (int isrc = 0; isrc < 4; ++isrc)
            for (int idst = 0; idst < 4; ++idst)
                if (isrc != idst) pool[idst] = mixf(pool[idst], hashmix(pool[isrc], hc));
        uint32_t st[8] = {};
        uint32_t hc2 = 0x8b51f9ddu;  // INIT_B
        for (int i = 0; i < 8; ++i) {
            uint32_t dv = pool[i & 3];
            dv ^= hc2; hc2 *= 0x58f38dedu; dv *= hc2; dv ^= dv >> 16;
            st[i] = dv;
        }
        const uint64_t v0 = (uint64_t)st[0] | ((uint64_t)st[1] << 32);
        const uint64_t v1 = (uint64_t)st[2] | ((uint64_t)st[3] << 32);
        const uint64_t v2 = (uint64_t)st[4] | ((uint64_t)st[5] << 32);
        const uint64_t v3 = (uint64_t)st[6] | ((uint64_t)st[7] << 32);
        const unsigned __int128 s = (((unsigned __int128)v0) << 64) | v1;
        const unsigned __int128 i_ = (((unsigned __int128)v2) << 64) | v3;
        state = 0; inc = (i_ << 1) | 1;
        step(); state += s; step();
        has_uint32 = false; uinteger = 0;
    }
    constexpr uint64_t next64() {
        step();
        const uint64_t hi = (uint64_t)(state >> 64), lo = (uint64_t)state;
        const uint64_t x = hi ^ lo;
        const unsigned rot = (unsigned)(state >> 122);
        return (x >> rot) | (x << ((64u - rot) & 63u));
    }
    constexpr uint32_t next32() {
        if (has_uint32) { has_uint32 = false; return uinteger; }
        const uint64_t n = next64();
        has_uint32 = true; uinteger = (uint32_t)(n >> 32);
        return (uint32_t)n;
    }
    constexpr uint32_t bounded_lemire32(uint32_t rng) {
        const uint32_t rng_excl = rng + 1u;
        uint64_t m = (uint64_t)next32() * (uint64_t)rng_excl;
        uint32_t leftover = (uint32_t)m;
        if (leftover < rng_excl) {
            const uint32_t threshold = (0xFFFFFFFFu - rng) % rng_excl;
            while (leftover < threshold) {
                m = (uint64_t)next32() * (uint64_t)rng_excl;
                leftover = (uint32_t)m;
            }
        }
        return (uint32_t)(m >> 32);
    }
    constexpr int64_t integers0(int64_t high) {
        const uint64_t rng = (uint64_t)(high - 1);
        if (rng == 0) return 0;  // no RNG consumption
        return (int64_t)bounded_lemire32((uint32_t)rng);
    }
};

// ===========================================================================
// Compile-time plan: distinct proper-subtree series (one scan each, computed
// once for the WHOLE forest), root formulas, levels, liveness slot allocation.
// w_s = x * prod_children C_child ; C_s = exclusive cumsum w_s.
// Root: T~_r = sum_t x * prod C_child. Series 0 = leaf (C0 = exclusive cumsum x).
// ===========================================================================
constexpr int NTREE = 32, MAXSER = 32, MAXROOT = 32, MAXFAC = 5, MAXSLOT = 12;

struct Plan {
    int nser, nroot, nslot, maxlvl;
    int lvl[MAXSER];
    int slot[MAXSER];
    int nfac[MAXSER];
    int fac[MAXSER][4];
    int rnfac[MAXROOT];
    int rfac[MAXROOT][MAXFAC];
    int rlvl[MAXROOT];
    int tree_root[NTREE];
};

constexpr Plan build_plan() {
    Plan P{};
    unsigned skey[MAXSER] = {}, rkey[MAXROOT] = {};
    P.nser = 1; skey[0] = (2u << 16) | 2u;  // leaf canonical code "10"
    P.nfac[0] = 0;
    P.nroot = 0;

    Pcg64 rng; rng.seed_default0();
    for (int t = 0; t < NTREE; ++t) {
        int par[6] = {0, 0, 0, 0, 0, 0};
        for (int i = 1; i <= 5; ++i) par[i] = (int)rng.integers0(i);
        int ch[6][5] = {}; int nch[6] = {};
        for (int i = 1; i <= 5; ++i) ch[par[i]][nch[par[i]]++] = i;

        int sid[6] = {}; unsigned keyn[6] = {};
        for (int i = 5; i >= 1; --i) {
            const int n = nch[i];
            unsigned ck[5] = {}; int cf[5] = {};
            for (int k = 0; k < n; ++k) { ck[k] = keyn[ch[i][k]]; cf[k] = sid[ch[i][k]]; }
            for (int a = 0; a < n; ++a)   // sort keys desc (canonical), ids asc (product order)
                for (int bq = a + 1; bq < n; ++bq) {
                    if (ck[bq] > ck[a]) { unsigned tmp = ck[a]; ck[a] = ck[bq]; ck[bq] = tmp; }
                    if (cf[bq] < cf[a]) { int tmp = cf[a]; cf[a] = cf[bq]; cf[bq] = tmp; }
                }
            unsigned bits = 1u, len = 1u;
            for (int k = 0; k < n; ++k) { bits = (bits << (ck[k] >> 16)) | (ck[k] & 0xffffu); len += ck[k] >> 16; }
            bits <<= 1; len += 1;
            const unsigned key = (len << 16) | bits;
            keyn[i] = key;
            int id = -1;
            for (int q = 0; q < P.nser; ++q) if (skey[q] == key) { id = q; break; }
            if (id < 0) {
                id = P.nser++;
                skey[id] = key; P.nfac[id] = n;
                for (int k = 0; k < n; ++k) P.fac[id][k] = cf[k];
            }
            sid[i] = id;
        }
        {   // root shape
            const int n = nch[0];
            unsigned ck[5] = {}; int cf[5] = {};
            for (int k = 0; k < n; ++k) { ck[k] = keyn[ch[0][k]]; cf[k] = sid[ch[0][k]]; }
            for (int a = 0; a < n; ++a)
                for (int bq = a + 1; bq < n; ++bq) {
                    if (ck[bq] > ck[a]) { unsigned tmp = ck[a]; ck[a] = ck[bq]; ck[bq] = tmp; }
                    if (cf[bq] < cf[a]) { int tmp = cf[a]; cf[a] = cf[bq]; cf[bq] = tmp; }
                }
            unsigned bits = 1u, len = 1u;
            for (int k = 0; k < n; ++k) { bits = (bits << (ck[k] >> 16)) | (ck[k] & 0xffffu); len += ck[k] >> 16; }
            bits <<= 1; len += 1;
            const unsigned key = (len << 16) | bits;
            int id = -1;
            for (int q = 0; q < P.nroot; ++q) if (rkey[q] == key) { id = q; break; }
            if (id < 0) {
                id = P.nroot++;
                rkey[id] = key; P.rnfac[id] = n;
                for (int k = 0; k < n; ++k) P.rfac[id][k] = cf[k];
            }
            P.tree_root[t] = id;
        }
    }
    // levels (factors always have smaller id -> single pass)
    P.lvl[0] = 0; P.maxlvl = 0;
    for (int s = 1; s < P.nser; ++s) {
        int m = 0;
        for (int k = 0; k < P.nfac[s]; ++k) { const int l = P.lvl[P.fac[s][k]]; if (l > m) m = l; }
        P.lvl[s] = m + 1;
        if (m + 1 > P.maxlvl) P.maxlvl = m + 1;
    }
    for (int r = 0; r < P.nroot; ++r) {
        int m = 0;
        for (int k = 0; k < P.rnfac[r]; ++k) { const int l = P.lvl[P.rfac[r][k]]; if (l > m) m = l; }
        P.rlvl[r] = m;
    }
    // last-use level per series
    int last[MAXSER] = {};
    for (int s = 0; s < P.nser; ++s) last[s] = 0;
    for (int s = 1; s < P.nser; ++s)
        for (int k = 0; k < P.nfac[s]; ++k) { const int f = P.fac[s][k]; if (P.lvl[s] > last[f]) last[f] = P.lvl[s]; }
    for (int r = 0; r < P.nroot; ++r)
        for (int k = 0; k < P.rnfac[r]; ++k) { const int f = P.rfac[r][k]; if (P.rlvl[r] > last[f]) last[f] = P.rlvl[r]; }
    // greedy slot allocation (free at last_use+1; dst of level L never aliases a
    // factor still consumed at level >= L because those have free_at >= L+1)
    int free_at[MAXSLOT] = {};
    for (int q = 0; q < MAXSLOT; ++q) free_at[q] = -1000;
    P.nslot = 0;
    for (int L = 0; L <= P.maxlvl; ++L)
        for (int s = 0; s < P.nser; ++s) {
            if (P.lvl[s] != L) continue;
            int pick = -1;
            for (int q = 0; q < MAXSLOT; ++q) if (free_at[q] <= L) { pick = q; break; }
            P.slot[s] = pick;
            free_at[pick] = last[s] + 1;
            if (pick + 1 > P.nslot) P.nslot = pick + 1;
        }
    return P;
}

constexpr Plan PL = build_plan();
static_assert(PL.nser <= MAXSER && PL.nroot <= MAXROOT, "plan overflow");
static_assert(PL.nslot <= MAXSLOT && PL.maxlvl <= 9, "plan overflow");
static_assert(PL.nslot >= 1 && PL.nser >= 1 && PL.nroot >= 1, "plan degenerate");

}  // namespace cx

// ===========================================================================
// Device: DPP wave scan (gfx9 canonical: row_shr 1/2/4/8 + row_bcast 15/31).
// Validated on-HW rounds 3-6.
// ===========================================================================
template <int CTRL, int RM>
__device__ __forceinline__ float dppmov(float x) {
    return __builtin_bit_cast(float,
        __builtin_amdgcn_update_dpp(0, __builtin_bit_cast(int, x), CTRL, RM, 0xf, false));
}
__device__ __forceinline__ float wave_incl_scan(float v) {
    v += dppmov<0x111, 0xf>(v);
    v += dppmov<0x112, 0xf>(v);
    v += dppmov<0x114, 0xf>(v);
    v += dppmov<0x118, 0xf>(v);
    v += dppmov<0x142, 0xa>(v);  // row_bcast:15 -> rows 1,3
    v += dppmov<0x143, 0xc>(v);  // row_bcast:31 -> rows 2,3
    return v;                    // inclusive; lane63 = wave total
}

struct OutMap { unsigned char m[32]; };

// ===========================================================================
// 512 threads x 8 elems/thread (T=4096). Fully unrolled from constexpr plan.
// Per level L: [pre: exclusive-local cumsum -> dst slot (FMA chain fusing the
// last factor), DPP wave scan, wave-total -> LDS] barrier [post: base += carry,
// S[ds][:] += base] [root reduces at rlvl L via FMA chains]; final barrier.
//
// launch_bounds: (512, 2) — VGPR cap 256. Round 6 lesson: (512, 6) forced a
// ~85-VGPR cap on ~100 floats of state -> full scratch spill (VGPR_Count=40,
// 165 MB scratch traffic, 3.3x regression). Never bound occupancy past the
// state footprint.
// ===========================================================================
#define THREADS 512
#define ELEM 8
#define NWAVE 8

__global__ __launch_bounds__(THREADS, 2) void fis_kernel(const float* __restrict__ x,
                                                         const float* __restrict__ alphas,
                                                         float* __restrict__ out,
                                                         const OutMap om) {
    using cx::PL;
    constexpr int NSER = PL.nser, NROOT = PL.nroot, NSLOT = PL.nslot, MAXL = PL.maxlvl;

    const int tid = threadIdx.x;
    const int lane = tid & 63;
    const int wv = tid >> 6;
    const int b = blockIdx.x >> 7;   // CH = 128
    const int c = blockIdx.x & 127;

    __shared__ float s_w[NSER + NROOT][NWAVE];

    float xr[ELEM];
    {
        const float4* xv = reinterpret_cast<const float4*>(
            x + (((size_t)b << 7) + (size_t)c) * 4096 + (size_t)tid * ELEM);
        const float4 v0 = xv[0], v1 = xv[1];
        xr[0] = v0.x; xr[1] = v0.y; xr[2] = v0.z; xr[3] = v0.w;
        xr[4] = v1.x; xr[5] = v1.y; xr[6] = v1.z; xr[7] = v1.w;
    }

    float S[NSLOT][ELEM];   // compile-time indexed after unroll -> registers
    float wex[cx::MAXSER];  // per-scan carried scalar (exclusive-in-wave offset)

#pragma unroll
    for (int L = 0; L <= MAXL; ++L) {
        // ---- pre-phase: scans at level L ----
#pragma unroll
        for (int s = 0; s < NSER; ++s) {
            if (PL.lvl[s] != L) continue;
            const int ds = PL.slot[s];
            float run = 0.f;
            if (PL.nfac[s] == 0) {
                // leaf series: exclusive local cumsum of x
#pragma unroll
                for (int j = 0; j < ELEM; ++j) { S[ds][j] = run; run += xr[j]; }
            } else {
                float v[ELEM];
#pragma unroll
                for (int j = 0; j < ELEM; ++j) v[j] = xr[j];
#pragma unroll
                for (int k = 0; k < 3; ++k) {          // all factors but the last
                    if (k < PL.nfac[s] - 1) {
                        const int fs = PL.slot[PL.fac[s][k]];
#pragma unroll
                        for (int j = 0; j < ELEM; ++j) v[j] *= S[fs][j];
                    }
                }
                const int fl = PL.slot[PL.fac[s][PL.nfac[s] - 1]];
#pragma unroll
                for (int j = 0; j < ELEM; ++j) {       // fused: run += v*C_last
                    S[ds][j] = run;
                    run = __builtin_fmaf(v[j], S[fl][j], run);
                }
            }
            const float wi = wave_incl_scan(run);
            if (lane == 63) s_w[s][wv] = wi;           // wave total
            wex[s] = wi - run;                         // exclusive within wave
        }
        __syncthreads();
        // ---- post-phase: finish exclusive cumsum ----
#pragma unroll
        for (int s = 0; s < NSER; ++s) {
            if (PL.lvl[s] != L) continue;
            const int ds = PL.slot[s];
            float base = wex[s];
#pragma unroll
            for (int k = 0; k < NWAVE - 1; ++k)
                if (k < wv) base += s_w[s][k];
#pragma unroll
            for (int j = 0; j < ELEM; ++j) S[ds][j] += base;
        }
        // ---- root reduces whose deepest factor is level L ----
#pragma unroll
        for (int r = 0; r < NROOT; ++r) {
            if (PL.rlvl[r] != L) continue;
            float v[ELEM];
#pragma unroll
            for (int j = 0; j < ELEM; ++j) v[j] = xr[j];
#pragma unroll
            for (int k = 0; k < 4; ++k) {              // all factors but the last
                if (k < PL.rnfac[r] - 1) {
                    const int fs = PL.slot[PL.rfac[r][k]];
#pragma unroll
                    for (int j = 0; j < ELEM; ++j) v[j] *= S[fs][j];
                }
            }
            const int fl = PL.slot[PL.rfac[r][PL.rnfac[r] - 1]];
            float acc = 0.f;
#pragma unroll
            for (int j = 0; j < ELEM; ++j) acc = __builtin_fmaf(v[j], S[fl][j], acc);
            const float wr = wave_incl_scan(acc);
            if (lane == 63) s_w[NSER + r][wv] = wr;    // per-wave partial
        }
    }

    __syncthreads();
    if (tid < 32) {
        const int rid = om.m[tid];
        float T = 0.f;
#pragma unroll
        for (int k = 0; k < NWAVE; ++k) T += s_w[NSER + rid][k];
        const float* ap = alphas + tid * 768 + c;  // alphas[tree, i, c] : [32,6,128]
        const float aprod = ap[0] * ap[128] * ap[256] * ap[384] * ap[512] * ap[640];
        out[(((size_t)b << 5) + (size_t)tid) * 128 + c] = aprod * T;
    }
}

// ===========================================================================
extern "C" void kernel_launch(void* const* d_in, const int* in_sizes, int n_in,
                              void* d_out, int out_size, void* d_ws, size_t ws_size,
                              hipStream_t stream) {
    const float* x = (const float*)d_in[0];       // [16,128,4096] f32
    const float* alphas = (const float*)d_in[1];  // [32,6,128]    f32
    float* out = (float*)d_out;                   // [16,32,128]   f32

    OutMap om;
    for (int t = 0; t < cx::NTREE; ++t) om.m[t] = (unsigned char)cx::PL.tree_root[t];

    fis_kernel<<<dim3(16 * 128), dim3(THREADS), 0, stream>>>(x, alphas, out, om);
}

// Round 10
// 18.910 us; speedup vs baseline: 3.4158x; 1.3108x over previous
//
#include <hip/hip_runtime.h>
#include <cstdint>
#include <cstddef>

// ===========================================================================
// Compile-time replication of numpy default_rng(0) forest generation
// (SeedSequence(0) -> PCG64 -> Generator.integers(0,i), Lemire int64 path).
// Validated on-HW rounds 2-7 (absmax ~1e6-1.7e7 vs 1.04e12 threshold).
// ===========================================================================
namespace cx {

constexpr uint32_t hashmix(uint32_t value, uint32_t& hc) {
    value ^= hc; hc *= 0x931e8875u; value *= hc; value ^= value >> 16; return value;
}
constexpr uint32_t mixf(uint32_t x, uint32_t y) {
    uint32_t r = x * 0xca01f9ddu - y * 0x4973f715u; r ^= r >> 16; return r;
}

struct Pcg64 {
    unsigned __int128 state{}, inc{};
    bool has_uint32{}; uint32_t uinteger{};
    static constexpr unsigned __int128 mult() {
        return (((unsigned __int128)2549297995355413924ULL) << 64) | 4865540595714422341ULL;
    }
    constexpr void step() { state = state * mult() + inc; }
    constexpr void seed_default0() {
        uint32_t pool[4] = {0, 0, 0, 0};
        uint32_t hc = 0x43b0d7e5u;  // INIT_A
        for (int i = 0; i < 4; ++i) pool[i] = hashmix(0u, hc);
        for (int isrc = 0; isrc < 4; ++isrc)
            for (int idst = 0; idst < 4; ++idst)
                if (isrc != idst) pool[idst] = mixf(pool[idst], hashmix(pool[isrc], hc));
        uint32_t st[8] = {};
        uint32_t hc2 = 0x8b51f9ddu;  // INIT_B
        for (int i = 0; i < 8; ++i) {
            uint32_t dv = pool[i & 3];
            dv ^= hc2; hc2 *= 0x58f38dedu; dv *= hc2; dv ^= dv >> 16;
            st[i] = dv;
        }
        const uint64_t v0 = (uint64_t)st[0] | ((uint64_t)st[1] << 32);
        const uint64_t v1 = (uint64_t)st[2] | ((uint64_t)st[3] << 32);
        const uint64_t v2 = (uint64_t)st[4] | ((uint64_t)st[5] << 32);
        const uint64_t v3 = (uint64_t)st[6] | ((uint64_t)st[7] << 32);
        const unsigned __int128 s = (((unsigned __int128)v0) << 64) | v1;
        const unsigned __int128 i_ = (((unsigned __int128)v2) << 64) | v3;
        state = 0; inc = (i_ << 1) | 1;
        step(); state += s; step();
        has_uint32 = false; uinteger = 0;
    }
    constexpr uint64_t next64() {
        step();
        const uint64_t hi = (uint64_t)(state >> 64), lo = (uint64_t)state;
        const uint64_t x = hi ^ lo;
        const unsigned rot = (unsigned)(state >> 122);
        return (x >> rot) | (x << ((64u - rot) & 63u));
    }
    constexpr uint32_t next32() {
        if (has_uint32) { has_uint32 = false; return uinteger; }
        const uint64_t n = next64();
        has_uint32 = true; uinteger = (uint32_t)(n >> 32);
        return (uint32_t)n;
    }
    constexpr uint32_t bounded_lemire32(uint32_t rng) {
        const uint32_t rng_excl = rng + 1u;
        uint64_t m = (uint64_t)next32() * (uint64_t)rng_excl;
        uint32_t leftover = (uint32_t)m;
        if (leftover < rng_excl) {
            const uint32_t threshold = (0xFFFFFFFFu - rng) % rng_excl;
            while (leftover < threshold) {
                m = (uint64_t)next32() * (uint64_t)rng_excl;
                leftover = (uint32_t)m;
            }
        }
        return (uint32_t)(m >> 32);
    }
    constexpr int64_t integers0(int64_t high) {
        const uint64_t rng = (uint64_t)(high - 1);
        if (rng == 0) return 0;  // no RNG consumption
        return (int64_t)bounded_lemire32((uint32_t)rng);
    }
};

// ===========================================================================
// Compile-time plan: distinct proper-subtree series (one scan each, computed
// once for the WHOLE forest), root formulas, levels, liveness slot allocation.
// w_s = x * prod_children C_child ; C_s = exclusive cumsum w_s.
// Root: T~_r = sum_t x * prod C_child. Series 0 = leaf (C0 = exclusive cumsum x).
// ===========================================================================
constexpr int NTREE = 32, MAXSER = 32, MAXROOT = 32, MAXFAC = 5, MAXSLOT = 12;

struct Plan {
    int nser, nroot, nslot, maxlvl;
    int lvl[MAXSER];
    int slot[MAXSER];
    int nfac[MAXSER];
    int fac[MAXSER][4];
    int rnfac[MAXROOT];
    int rfac[MAXROOT][MAXFAC];
    int rlvl[MAXROOT];
    int tree_root[NTREE];
};

constexpr Plan build_plan() {
    Plan P{};
    unsigned skey[MAXSER] = {}, rkey[MAXROOT] = {};
    P.nser = 1; skey[0] = (2u << 16) | 2u;  // leaf canonical code "10"
    P.nfac[0] = 0;
    P.nroot = 0;

    Pcg64 rng; rng.seed_default0();
    for (int t = 0; t < NTREE; ++t) {
        int par[6] = {0, 0, 0, 0, 0, 0};
        for (int i = 1; i <= 5; ++i) par[i] = (int)rng.integers0(i);
        int ch[6][5] = {}; int nch[6] = {};
        for (int i = 1; i <= 5; ++i) ch[par[i]][nch[par[i]]++] = i;

        int sid[6] = {}; unsigned keyn[6] = {};
        for (int i = 5; i >= 1; --i) {
            const int n = nch[i];
            unsigned ck[5] = {}; int cf[5] = {};
            for (int k = 0; k < n; ++k) { ck[k] = keyn[ch[i][k]]; cf[k] = sid[ch[i][k]]; }
            for (int a = 0; a < n; ++a)   // sort keys desc (canonical), ids asc (product order)
                for (int bq = a + 1; bq < n; ++bq) {
                    if (ck[bq] > ck[a]) { unsigned tmp = ck[a]; ck[a] = ck[bq]; ck[bq] = tmp; }
                    if (cf[bq] < cf[a]) { int tmp = cf[a]; cf[a] = cf[bq]; cf[bq] = tmp; }
                }
            unsigned bits = 1u, len = 1u;
            for (int k = 0; k < n; ++k) { bits = (bits << (ck[k] >> 16)) | (ck[k] & 0xffffu); len += ck[k] >> 16; }
            bits <<= 1; len += 1;
            const unsigned key = (len << 16) | bits;
            keyn[i] = key;
            int id = -1;
            for (int q = 0; q < P.nser; ++q) if (skey[q] == key) { id = q; break; }
            if (id < 0) {
                id = P.nser++;
                skey[id] = key; P.nfac[id] = n;
                for (int k = 0; k < n; ++k) P.fac[id][k] = cf[k];
            }
            sid[i] = id;
        }
        {   // root shape
            const int n = nch[0];
            unsigned ck[5] = {}; int cf[5] = {};
            for (int k = 0; k < n; ++k) { ck[k] = keyn[ch[0][k]]; cf[k] = sid[ch[0][k]]; }
            for (int a = 0; a < n; ++a)
                for (int bq = a + 1; bq < n; ++bq) {
                    if (ck[bq] > ck[a]) { unsigned tmp = ck[a]; ck[a] = ck[bq]; ck[bq] = tmp; }
                    if (cf[bq] < cf[a]) { int tmp = cf[a]; cf[a] = cf[bq]; cf[bq] = tmp; }
                }
            unsigned bits = 1u, len = 1u;
            for (int k = 0; k < n; ++k) { bits = (bits << (ck[k] >> 16)) | (ck[k] & 0xffffu); len += ck[k] >> 16; }
            bits <<= 1; len += 1;
            const unsigned key = (len << 16) | bits;
            int id = -1;
            for (int q = 0; q < P.nroot; ++q) if (rkey[q] == key) { id = q; break; }
            if (id < 0) {
                id = P.nroot++;
                rkey[id] = key; P.rnfac[id] = n;
                for (int k = 0; k < n; ++k) P.rfac[id][k] = cf[k];
            }
            P.tree_root[t] = id;
        }
    }
    // levels (factors always have smaller id -> single pass)
    P.lvl[0] = 0; P.maxlvl = 0;
    for (int s = 1; s < P.nser; ++s) {
        int m = 0;
        for (int k = 0; k < P.nfac[s]; ++k) { const int l = P.lvl[P.fac[s][k]]; if (l > m) m = l; }
        P.lvl[s] = m + 1;
        if (m + 1 > P.maxlvl) P.maxlvl = m + 1;
    }
    for (int r = 0; r < P.nroot; ++r) {
        int m = 0;
        for (int k = 0; k < P.rnfac[r]; ++k) { const int l = P.lvl[P.rfac[r][k]]; if (l > m) m = l; }
        P.rlvl[r] = m;
    }
    // last-use level per series
    int last[MAXSER] = {};
    for (int s = 0; s < P.nser; ++s) last[s] = 0;
    for (int s = 1; s < P.nser; ++s)
        for (int k = 0; k < P.nfac[s]; ++k) { const int f = P.fac[s][k]; if (P.lvl[s] > last[f]) last[f] = P.lvl[s]; }
    for (int r = 0; r < P.nroot; ++r)
        for (int k = 0; k < P.rnfac[r]; ++k) { const int f = P.rfac[r][k]; if (P.rlvl[r] > last[f]) last[f] = P.rlvl[r]; }
    // greedy slot allocation (free at last_use+1; dst of level L never aliases a
    // factor still consumed at level >= L because those have free_at >= L+1)
    int free_at[MAXSLOT] = {};
    for (int q = 0; q < MAXSLOT; ++q) free_at[q] = -1000;
    P.nslot = 0;
    for (int L = 0; L <= P.maxlvl; ++L)
        for (int s = 0; s < P.nser; ++s) {
            if (P.lvl[s] != L) continue;
            int pick = -1;
            for (int q = 0; q < MAXSLOT; ++q) if (free_at[q] <= L) { pick = q; break; }
            P.slot[s] = pick;
            free_at[pick] = last[s] + 1;
            if (pick + 1 > P.nslot) P.nslot = pick + 1;
        }
    return P;
}

constexpr Plan PL = build_plan();
static_assert(PL.nser <= MAXSER && PL.nroot <= MAXROOT, "plan overflow");
static_assert(PL.nslot <= MAXSLOT && PL.maxlvl <= 9, "plan overflow");
static_assert(PL.nslot >= 1 && PL.nser >= 1 && PL.nroot >= 1, "plan degenerate");

}  // namespace cx

// ===========================================================================
// Device: DPP wave scan (gfx9 canonical: row_shr 1/2/4/8 + row_bcast 15/31).
// Validated on-HW rounds 3-7.
// ===========================================================================
template <int CTRL, int RM>
__device__ __forceinline__ float dppmov(float x) {
    return __builtin_bit_cast(float,
        __builtin_amdgcn_update_dpp(0, __builtin_bit_cast(int, x), CTRL, RM, 0xf, false));
}
__device__ __forceinline__ float wave_incl_scan(float v) {
    v += dppmov<0x111, 0xf>(v);
    v += dppmov<0x112, 0xf>(v);
    v += dppmov<0x114, 0xf>(v);
    v += dppmov<0x118, 0xf>(v);
    v += dppmov<0x142, 0xa>(v);  // row_bcast:15 -> rows 1,3
    v += dppmov<0x143, 0xc>(v);  // row_bcast:31 -> rows 2,3
    return v;                    // inclusive; lane63 = wave total
}

struct OutMap { unsigned char m[32]; };

typedef float v2f __attribute__((ext_vector_type(2)));

// ===========================================================================
// 256 threads x 16 elems/thread (T=4096), elems held as 8x float2 so the
// element-parallel products / root FMA-reduces can emit packed VOP3P
// (v_pk_mul_f32 / v_pk_fma_f32); the loop-carried cumsum chain stays scalar.
// Per level L: [pre: packed products, scalar fused inclusive cumsum -> dst
// slot, DPP wave scan, wave-total -> LDS] barrier [post: base = wex + carry,
// descending shift S_excl[j] = base + S_incl[j-1]] [packed root reduces at
// rlvl L]; final barrier; epilogue.
//
// Round 6 lesson (VGPR_Count=40, 165 MB scratch traffic, 3.3x regression):
// never __launch_bounds__-bound occupancy past the state footprint.
// Round 7 lesson: 512x8 loses to 256x16 — wave-scan/barrier overhead
// amortizes over half the payload and total wave count doubles.
// ===========================================================================
#define THREADS 256
#define VECN 8      // 8 x float2 = 16 elems
#define NWAVE 4

__global__ __launch_bounds__(THREADS) void fis_kernel(const float* __restrict__ x,
                                                      const float* __restrict__ alphas,
                                                      float* __restrict__ out,
                                                      const OutMap om) {
    using cx::PL;
    constexpr int NSER = PL.nser, NROOT = PL.nroot, NSLOT = PL.nslot, MAXL = PL.maxlvl;

    const int tid = threadIdx.x;
    const int lane = tid & 63;
    const int wv = tid >> 6;
    const int b = blockIdx.x >> 7;   // CH = 128
    const int c = blockIdx.x & 127;

    __shared__ float s_w[NSER + NROOT][NWAVE];

    v2f xr[VECN];
    {
        const float4* xv = reinterpret_cast<const float4*>(
            x + (((size_t)b << 7) + (size_t)c) * 4096 + (size_t)tid * 16);
#pragma unroll
        for (int j = 0; j < 4; ++j) {
            const float4 v = xv[j];
            xr[2 * j + 0] = v2f{v.x, v.y};
            xr[2 * j + 1] = v2f{v.z, v.w};
        }
    }

    v2f S[NSLOT][VECN];     // compile-time indexed after unroll -> registers
    float wex[cx::MAXSER];  // per-scan carried scalar (exclusive-in-wave offset)
    float tot[cx::MAXSER];

#pragma unroll
    for (int L = 0; L <= MAXL; ++L) {
        // ---- pre-phase: scans at level L ----
#pragma unroll
        for (int s = 0; s < NSER; ++s) {
            if (PL.lvl[s] != L) continue;
            const int ds = PL.slot[s];
            float run = 0.f;
            if (PL.nfac[s] == 0) {
                // leaf series: inclusive local cumsum of x (scalar chain, SSA)
#pragma unroll
                for (int j = 0; j < VECN; ++j) {
                    const float a = run + xr[j].x;
                    const float b2 = a + xr[j].y;
                    S[ds][j] = v2f{a, b2};
                    run = b2;
                }
            } else {
                v2f v[VECN];
#pragma unroll
                for (int j = 0; j < VECN; ++j) v[j] = xr[j];
#pragma unroll
                for (int k = 0; k < 3; ++k) {          // all factors but the last: packed mul
                    if (k < PL.nfac[s] - 1) {
                        const int fs = PL.slot[PL.fac[s][k]];
#pragma unroll
                        for (int j = 0; j < VECN; ++j) v[j] *= S[fs][j];
                    }
                }
                const int fl = PL.slot[PL.fac[s][PL.nfac[s] - 1]];
#pragma unroll
                for (int j = 0; j < VECN; ++j) {       // fused scalar chain: run += v*C_last
                    const float a = __builtin_fmaf(v[j].x, S[fl][j].x, run);
                    const float b2 = __builtin_fmaf(v[j].y, S[fl][j].y, a);
                    S[ds][j] = v2f{a, b2};             // inclusive local
                    run = b2;
                }
            }
            tot[s] = run;
            const float wi = wave_incl_scan(run);
            if (lane == 63) s_w[s][wv] = wi;           // wave total
            wex[s] = wi - run;                         // exclusive within wave
        }
        __syncthreads();
        // ---- post-phase: exclusive = base + inclusive[j-1] (descending shift) ----
#pragma unroll
        for (int s = 0; s < NSER; ++s) {
            if (PL.lvl[s] != L) continue;
            const int ds = PL.slot[s];
            float base = wex[s];
#pragma unroll
            for (int k = 0; k < NWAVE - 1; ++k)
                if (k < wv) base += s_w[s][k];
#pragma unroll
            for (int j = VECN - 1; j >= 1; --j) {
                S[ds][j].y = base + S[ds][j].x;
                S[ds][j].x = base + S[ds][j - 1].y;
            }
            S[ds][0].y = base + S[ds][0].x;
            S[ds][0].x = base;
        }
        // ---- root reduces whose deepest factor is level L (packed FMA) ----
#pragma unroll
        for (int r = 0; r < NROOT; ++r) {
            if (PL.rlvl[r] != L) continue;
            v2f v[VECN];
#pragma unroll
            for (int j = 0; j < VECN; ++j) v[j] = xr[j];
#pragma unroll
            for (int k = 0; k < 4; ++k) {              // all factors but the last: packed mul
                if (k < PL.rnfac[r] - 1) {
                    const int fs = PL.slot[PL.rfac[r][k]];
#pragma unroll
                    for (int j = 0; j < VECN; ++j) v[j] *= S[fs][j];
                }
            }
            const int fl = PL.slot[PL.rfac[r][PL.rnfac[r] - 1]];
            v2f acc = v2f{0.f, 0.f};
#pragma unroll
            for (int j = 0; j < VECN; ++j) acc += v[j] * S[fl][j];  // packed fma
            const float wr = wave_incl_scan(acc.x + acc.y);
            if (lane == 63) s_w[NSER + r][wv] = wr;    // per-wave partial
        }
    }

    __syncthreads();
    if (tid < 32) {
        const int rid = om.m[tid];
        float T = 0.f;
#pragma unroll
        for (int k = 0; k < NWAVE; ++k) T += s_w[NSER + rid][k];
        const float* ap = alphas + tid * 768 + c;  // alphas[tree, i, c] : [32,6,128]
        const float aprod = ap[0] * ap[128] * ap[256] * ap[384] * ap[512] * ap[640];
        out[(((size_t)b << 5) + (size_t)tid) * 128 + c] = aprod * T;
    }
}

// ===========================================================================
extern "C" void kernel_launch(void* const* d_in, const int* in_sizes, int n_in,
                              void* d_out, int out_size, void* d_ws, size_t ws_size,
                              hipStream_t stream) {
    const float* x = (const float*)d_in[0];       // [16,128,4096] f32
    const float* alphas = (const float*)d_in[1];  // [32,6,128]    f32
    float* out = (float*)d_out;                   // [16,32,128]   f32

    OutMap om;
    for (int t = 0; t < cx::NTREE; ++t) om.m[t] = (unsigned char)cx::PL.tree_root[t];

    fis_kernel<<<dim3(16 * 128), dim3(THREADS), 0, stream>>>(x, alphas, out, om);
}